// Round 1
// baseline (166.962 us; speedup 1.0000x reference)
//
#include <hip/hip_runtime.h>

// Problem geometry: inputs [B=32, H=128, W=128, C=128] fp32, STRIDE=2.
// comps[k] = inputs[:, i::2, j::2, :], k = i*2 + j. Output 0: comps[argmax L2]
// shape [32,64,64,128] fp32 (16,777,216 elems). Output 1: index (1 elem, as float).

#define IN_F4   16777216   // 32*128*128*128 / 4
#define OUT_F4   4194304   // 32*64*64*128 / 4
#define OUT_ELEMS 16777216

// Pass 1: per-component sums of squares.
// float4 index v -> flat float index 4v. Floats per w-step: 128 (>>5 in f4),
// floats per h-step: 16384 (>>12 in f4). Component k = hpar*2 + wpar.
__global__ void __launch_bounds__(256) sums_kernel(const float4* __restrict__ in,
                                                   double* __restrict__ sums) {
    float a0 = 0.f, a1 = 0.f, a2 = 0.f, a3 = 0.f;
    const int stride = gridDim.x * blockDim.x;
    for (int v = blockIdx.x * blockDim.x + threadIdx.x; v < IN_F4; v += stride) {
        float4 x = in[v];
        float s = x.x * x.x + x.y * x.y + x.z * x.z + x.w * x.w;
        int wpar = (v >> 5) & 1;
        int hpar = (v >> 12) & 1;
        int k = hpar * 2 + wpar;
        a0 += (k == 0) ? s : 0.f;
        a1 += (k == 1) ? s : 0.f;
        a2 += (k == 2) ? s : 0.f;
        a3 += (k == 3) ? s : 0.f;
    }
    // wave64 butterfly reduce
    for (int off = 32; off > 0; off >>= 1) {
        a0 += __shfl_down(a0, off, 64);
        a1 += __shfl_down(a1, off, 64);
        a2 += __shfl_down(a2, off, 64);
        a3 += __shfl_down(a3, off, 64);
    }
    __shared__ float lds[4][4];   // [wave][component], 256 threads = 4 waves
    const int wave = threadIdx.x >> 6;
    const int lane = threadIdx.x & 63;
    if (lane == 0) {
        lds[wave][0] = a0; lds[wave][1] = a1; lds[wave][2] = a2; lds[wave][3] = a3;
    }
    __syncthreads();
    if (threadIdx.x == 0) {
        double s0 = 0, s1 = 0, s2 = 0, s3 = 0;
        const int nw = blockDim.x >> 6;
        for (int w = 0; w < nw; ++w) {
            s0 += lds[w][0]; s1 += lds[w][1]; s2 += lds[w][2]; s3 += lds[w][3];
        }
        atomicAdd(&sums[0], s0);
        atomicAdd(&sums[1], s1);
        atomicAdd(&sums[2], s2);
        atomicAdd(&sums[3], s3);
    }
}

// Pass 2: argmax of the 4 sums (sqrt is monotone -> compare sums directly).
// First-max wins, matching jnp.argmax tie-breaking.
__global__ void pick_kernel(const double* __restrict__ sums,
                            int* __restrict__ idx,
                            float* __restrict__ out_idx) {
    double best = sums[0];
    int bi = 0;
    for (int k = 1; k < 4; ++k) {
        if (sums[k] > best) { best = sums[k]; bi = k; }
    }
    *idx = bi;
    *out_idx = (float)bi;
}

// Pass 3: gather comps[idx] -> out. Output f4 layout:
//   c4 = o & 31 (32 f4 per C-row), w' = (o>>5)&63, h' = (o>>11)&63, b = o>>17.
// Input f4 index: b*524288 + (2h'+i)*4096 + (2w'+j)*32 + c4.
__global__ void __launch_bounds__(256) gather_kernel(const float4* __restrict__ in,
                                                     float4* __restrict__ out,
                                                     const int* __restrict__ idxp) {
    const int k = *idxp;
    const int i = k >> 1;
    const int j = k & 1;
    const int stride = gridDim.x * blockDim.x;
    for (int o = blockIdx.x * blockDim.x + threadIdx.x; o < OUT_F4; o += stride) {
        int c4 = o & 31;
        int wq = (o >> 5) & 63;
        int hq = (o >> 11) & 63;
        int b  = o >> 17;
        int vin = b * 524288 + (2 * hq + i) * 4096 + (2 * wq + j) * 32 + c4;
        out[o] = in[vin];
    }
}

extern "C" void kernel_launch(void* const* d_in, const int* in_sizes, int n_in,
                              void* d_out, int out_size, void* d_ws, size_t ws_size,
                              hipStream_t stream) {
    const float4* in = (const float4*)d_in[0];
    float* out = (float*)d_out;
    double* sums = (double*)d_ws;
    int* idx = (int*)((char*)d_ws + 32);

    // Zero the accumulators every call (harness poisons ws once, never re-poisons;
    // we accumulate with atomics so must start from 0 deterministically).
    hipMemsetAsync(d_ws, 0, 64, stream);

    sums_kernel<<<2048, 256, 0, stream>>>(in, sums);
    pick_kernel<<<1, 1, 0, stream>>>(sums, idx, out + OUT_ELEMS);
    gather_kernel<<<2048, 256, 0, stream>>>(in, (float4*)out, idx);
}

// Round 2
// 89.505 us; speedup vs baseline: 1.8654x; 1.8654x over previous
//
#include <hip/hip_runtime.h>

// Geometry: inputs [B=32, H=128, W=128, C=128] fp32, STRIDE=2.
// comps[k] = inputs[:, i::2, j::2, :], k = i*2 + j.
// Out 0: comps[argmax L2] = [32,64,64,128] fp32 (16,777,216 elems). Out 1: index (float).

#define IN_F4   16777216   // 32*128*128*128 / 4
#define OUT_F4   4194304   // 32*64*64*128 / 4
#define OUT_ELEMS 16777216
#define NT       524288    // 2048 blocks * 256 threads

// Pass 1: sums of squares. Key structure: for v = tid + m*NT (NT = 2^19),
// w-parity = bit5(v) = bit5(tid), h-parity = bit12(v) = bit12(tid) — constant
// per thread. So each thread owns ONE component; 8 loads in flight per wave.
// Per wave: lanes 0-31 have wpar=0, lanes 32-63 wpar=1 (bit5 = lane bit5).
// Per block: hpar = (blockIdx>>4)&1 (bit12 of tid = bit4 of blockIdx).
__global__ void __launch_bounds__(256) sums_kernel(const float4* __restrict__ in,
                                                   float* __restrict__ partials) {
    const int tid = blockIdx.x * 256 + threadIdx.x;
    float acc = 0.f;
#pragma unroll
    for (int mo = 0; mo < 32; mo += 8) {
        float4 x0 = in[tid + (mo + 0) * NT];
        float4 x1 = in[tid + (mo + 1) * NT];
        float4 x2 = in[tid + (mo + 2) * NT];
        float4 x3 = in[tid + (mo + 3) * NT];
        float4 x4 = in[tid + (mo + 4) * NT];
        float4 x5 = in[tid + (mo + 5) * NT];
        float4 x6 = in[tid + (mo + 6) * NT];
        float4 x7 = in[tid + (mo + 7) * NT];
        acc += x0.x * x0.x + x0.y * x0.y + x0.z * x0.z + x0.w * x0.w;
        acc += x1.x * x1.x + x1.y * x1.y + x1.z * x1.z + x1.w * x1.w;
        acc += x2.x * x2.x + x2.y * x2.y + x2.z * x2.z + x2.w * x2.w;
        acc += x3.x * x3.x + x3.y * x3.y + x3.z * x3.z + x3.w * x3.w;
        acc += x4.x * x4.x + x4.y * x4.y + x4.z * x4.z + x4.w * x4.w;
        acc += x5.x * x5.x + x5.y * x5.y + x5.z * x5.z + x5.w * x5.w;
        acc += x6.x * x6.x + x6.y * x6.y + x6.z * x6.z + x6.w * x6.w;
        acc += x7.x * x7.x + x7.y * x7.y + x7.z * x7.z + x7.w * x7.w;
    }
    // Reduce each 32-lane half independently (xor masks 1..16 keep bit5 fixed).
    for (int off = 16; off >= 1; off >>= 1)
        acc += __shfl_xor(acc, off, 64);
    __shared__ float lds[4][2];  // [wave][wpar]
    const int lane = threadIdx.x & 63;
    const int wave = threadIdx.x >> 6;
    if (lane == 0)  lds[wave][0] = acc;
    if (lane == 32) lds[wave][1] = acc;
    __syncthreads();
    if (threadIdx.x < 2) {
        float s = lds[0][threadIdx.x] + lds[1][threadIdx.x] +
                  lds[2][threadIdx.x] + lds[3][threadIdx.x];
        // partials entry e = blockIdx*2 + wpar: k(e) = 2*bit5(e) + bit0(e)
        partials[blockIdx.x * 2 + threadIdx.x] = s;
    }
}

// Pass 2: reduce 4096 partials -> 4 sums, argmax (first-max, strict >).
// Entry e: k = 2*((e>>5)&1) + (e&1). Thread t strides by 256 -> bits 0..7
// constant -> k constant per thread = 2*((t>>5)&1) + (t&1).
__global__ void pick_kernel(const float* __restrict__ partials,
                            int* __restrict__ idx,
                            float* __restrict__ out_idx) {
    const int t = threadIdx.x;
    double s = 0.0;
    for (int m = 0; m < 4096; m += 256) s += (double)partials[t + m];
    // Collapse bits 1..4 (xor 2,4,8,16 preserve bit0 and bit5).
    for (int off = 2; off <= 16; off <<= 1)
        s += __shfl_xor(s, off, 64);
    __shared__ double lds[4][4];  // [wave][k]
    const int lane = t & 63;
    const int wave = t >> 6;
    const int k = 2 * ((lane >> 5) & 1) + (lane & 1);
    if (lane == 0 || lane == 1 || lane == 32 || lane == 33) lds[wave][k] = s;
    __syncthreads();
    if (t == 0) {
        double best = -1.0;
        int bi = 0;
        for (int kk = 0; kk < 4; ++kk) {
            double sk = lds[0][kk] + lds[1][kk] + lds[2][kk] + lds[3][kk];
            if (sk > best) { best = sk; bi = kk; }
        }
        *idx = bi;
        *out_idx = (float)bi;
    }
}

// Pass 3: gather comps[idx] -> out, 8 independent load/store pairs per thread.
__global__ void __launch_bounds__(256) gather_kernel(const float4* __restrict__ in,
                                                     float4* __restrict__ out,
                                                     const int* __restrict__ idxp) {
    const int k = *idxp;
    const int i = k >> 1;
    const int j = k & 1;
    const int tid = blockIdx.x * 256 + threadIdx.x;
#pragma unroll
    for (int m = 0; m < 8; ++m) {
        int o = tid + m * NT;
        int c4 = o & 31;
        int wq = (o >> 5) & 63;
        int hq = (o >> 11) & 63;
        int b  = o >> 17;
        int vin = b * 524288 + (2 * hq + i) * 4096 + (2 * wq + j) * 32 + c4;
        out[o] = in[vin];
    }
}

extern "C" void kernel_launch(void* const* d_in, const int* in_sizes, int n_in,
                              void* d_out, int out_size, void* d_ws, size_t ws_size,
                              hipStream_t stream) {
    const float4* in = (const float4*)d_in[0];
    float* out = (float*)d_out;
    float* partials = (float*)d_ws;                    // 4096 floats = 16 KB
    int* idx = (int*)((char*)d_ws + 16384);

    sums_kernel<<<2048, 256, 0, stream>>>(in, partials);
    pick_kernel<<<1, 256, 0, stream>>>(partials, idx, out + OUT_ELEMS);
    gather_kernel<<<2048, 256, 0, stream>>>(in, (float4*)out, idx);
}

// Round 4
// 88.820 us; speedup vs baseline: 1.8798x; 1.0077x over previous
//
#include <hip/hip_runtime.h>

// Geometry: inputs [B=32, H=128, W=128, C=128] fp32, STRIDE=2.
// comps[k] = inputs[:, i::2, j::2, :], k = i*2 + j.
// Out 0: comps[argmax L2] = [32,64,64,128] fp32 (16,777,216 elems). Out 1: index (float).

#define IN_F4     16777216   // 32*128*128*128 / 4
#define OUT_F4     4194304   // 32*64*64*128 / 4
#define OUT_ELEMS 16777216
#define NT        524288     // 2048 blocks * 256 threads = 2^19

// Pass 1: sums of squares. For v = tid + m*NT (NT = 2^19), bit5(v) = bit5(tid)
// (w-parity) and bit12(v) = bit12(tid) (h-parity) — each thread owns exactly
// one polyphase component. 16 independent loads in flight per wave.
// launch_bounds(256,2): VGPR cap 256 — no spill risk for the 16-deep unroll;
// compiler's actual allocation (~110) still yields 4 blocks/CU.
__global__ void __launch_bounds__(256, 2) sums_kernel(const float4* __restrict__ in,
                                                      float* __restrict__ partials) {
    const int tid  = blockIdx.x * 256 + threadIdx.x;
    const int lane = threadIdx.x & 63;
    const int wave = threadIdx.x >> 6;
    float acc = 0.f;
    for (int mo = 0; mo < 32; mo += 16) {
#pragma unroll
        for (int u = 0; u < 16; ++u) {
            float4 x = in[tid + (mo + u) * NT];
            acc += x.x * x.x + x.y * x.y + x.z * x.z + x.w * x.w;
        }
    }
    // Reduce each 32-lane half independently (xor 1..16 keeps bit5 fixed).
    for (int off = 16; off >= 1; off >>= 1)
        acc += __shfl_xor(acc, off, 64);
    __shared__ float plds[4][2];   // [wave][wpar]
    if (lane == 0)  plds[wave][0] = acc;
    if (lane == 32) plds[wave][1] = acc;
    __syncthreads();
    if (threadIdx.x < 2) {
        // partials entry e = blockIdx*2 + wpar: k(e) = 2*bit5(e) + bit0(e)
        // (bit5(e) = bit4(blockIdx) = bit12(tid) = h-parity).
        partials[blockIdx.x * 2 + threadIdx.x] =
            plds[0][threadIdx.x] + plds[1][threadIdx.x] +
            plds[2][threadIdx.x] + plds[3][threadIdx.x];
    }
}

// Pass 2 (fused): every block redundantly reduces all 4096 partials with
// IDENTICAL double-precision arithmetic -> identical argmax in every block
// (no cross-block broadcast needed). Then gathers comps[k] -> out.
__global__ void __launch_bounds__(256, 2) pick_gather_kernel(const float4* __restrict__ in,
                                                             float4* __restrict__ out,
                                                             const float* __restrict__ partials) {
    const int lane = threadIdx.x & 63;
    const int wave = threadIdx.x >> 6;
    __shared__ double klds[4][4];  // [wave][k]
    __shared__ int sidx;
    {
        // Entry e = t + 256*m: bits 0..7 of e fixed per thread ->
        // k = 2*bit5(t) + bit0(t), constant per thread.
        const int t = threadIdx.x;
        double s = 0.0;
        for (int m = 0; m < 4096; m += 256) s += (double)partials[t + m];
        // Collapse lane bits 1..4 (xor 2,4,8,16 preserve bit0 and bit5).
        for (int off = 2; off <= 16; off <<= 1)
            s += __shfl_xor(s, off, 64);
        const int kk = 2 * ((lane >> 5) & 1) + (lane & 1);
        if (lane == 0 || lane == 1 || lane == 32 || lane == 33) klds[wave][kk] = s;
        __syncthreads();
        if (t == 0) {
            double best = -1.0;
            int bi = 0;
            for (int q = 0; q < 4; ++q) {
                double sq = klds[0][q] + klds[1][q] + klds[2][q] + klds[3][q];
                if (sq > best) { best = sq; bi = q; }   // first-max, matches jnp.argmax
            }
            sidx = bi;
            if (blockIdx.x == 0) ((float*)out)[OUT_ELEMS] = (float)bi;
        }
        __syncthreads();
    }
    const int k = sidx;
    const int i = k >> 1;
    const int j = k & 1;
    const int tid = blockIdx.x * 256 + threadIdx.x;
#pragma unroll
    for (int m = 0; m < 8; ++m) {
        int o  = tid + m * NT;
        int c4 = o & 31;
        int wq = (o >> 5) & 63;
        int hq = (o >> 11) & 63;
        int b  = o >> 17;
        int vin = b * 524288 + (2 * hq + i) * 4096 + (2 * wq + j) * 32 + c4;
        out[o] = in[vin];
    }
}

extern "C" void kernel_launch(void* const* d_in, const int* in_sizes, int n_in,
                              void* d_out, int out_size, void* d_ws, size_t ws_size,
                              hipStream_t stream) {
    const float4* in = (const float4*)d_in[0];
    float4* out = (float4*)d_out;
    float* partials = (float*)d_ws;   // 4096 floats, fully rewritten every call

    sums_kernel<<<2048, 256, 0, stream>>>(in, partials);
    pick_gather_kernel<<<2048, 256, 0, stream>>>(in, out, partials);
}

// Round 6
// 81.084 us; speedup vs baseline: 2.0591x; 1.0954x over previous
//
#include <hip/hip_runtime.h>

// Geometry: inputs [B=32, H=128, W=128, C=128] fp32, STRIDE=2.
// comps[k] = inputs[:, i::2, j::2, :], k = i*2 + j.
// Out 0: comps[argmax L2] = [32,64,64,128] fp32 (16,777,216 elems). Out 1: index (float).

#define IN_F4     16777216   // 32*128*128*128 / 4
#define OUT_F4     4194304   // 32*64*64*128 / 4
#define OUT_ELEMS 16777216
#define NT        524288     // 2048 blocks * 256 threads = 2^19

typedef float nfloat4 __attribute__((ext_vector_type(4)));  // native vec for nontemporal builtin

// Pass 1: sums of squares, ascending sweep (leaves the input's TAIL hot in L3).
// For v = tid + m*NT (NT = 2^19), bit5(v) = bit5(tid) (w-parity) and
// bit12(v) = bit12(tid) (h-parity) — each thread owns exactly one component.
__global__ void __launch_bounds__(256, 2) sums_kernel(const float4* __restrict__ in,
                                                      float* __restrict__ partials) {
    const int tid  = blockIdx.x * 256 + threadIdx.x;
    const int lane = threadIdx.x & 63;
    const int wave = threadIdx.x >> 6;
    float acc = 0.f;
    for (int mo = 0; mo < 32; mo += 16) {
#pragma unroll
        for (int u = 0; u < 16; ++u) {
            float4 x = in[tid + (mo + u) * NT];
            acc += x.x * x.x + x.y * x.y + x.z * x.z + x.w * x.w;
        }
    }
    // Reduce each 32-lane half independently (xor 1..16 keeps bit5 fixed).
    for (int off = 16; off >= 1; off >>= 1)
        acc += __shfl_xor(acc, off, 64);
    __shared__ float plds[4][2];   // [wave][wpar]
    if (lane == 0)  plds[wave][0] = acc;
    if (lane == 32) plds[wave][1] = acc;
    __syncthreads();
    if (threadIdx.x < 2) {
        // partials entry e = blockIdx*2 + wpar: k(e) = 2*bit5(e) + bit0(e)
        // (bit5(e) = bit4(blockIdx) = bit12(tid) = h-parity).
        partials[blockIdx.x * 2 + threadIdx.x] =
            plds[0][threadIdx.x] + plds[1][threadIdx.x] +
            plds[2][threadIdx.x] + plds[3][threadIdx.x];
    }
}

// Pass 2 (fused): every block redundantly reduces all 4096 partials with
// IDENTICAL double-precision arithmetic -> identical argmax in every block.
// Then gathers comps[k] -> out in DESCENDING address order (reads the
// L3-hot tail first) with non-temporal stores (output is never re-read;
// keep it out of L3 so it doesn't evict the input we're still reading).
__global__ void __launch_bounds__(256, 2) pick_gather_kernel(const float4* __restrict__ in,
                                                             float4* __restrict__ out,
                                                             const float* __restrict__ partials) {
    const int lane = threadIdx.x & 63;
    const int wave = threadIdx.x >> 6;
    __shared__ double klds[4][4];  // [wave][k]
    __shared__ int sidx;
    {
        // Entry e = t + 256*m: bits 0..7 of e fixed per thread ->
        // k = 2*bit5(t) + bit0(t), constant per thread.
        const int t = threadIdx.x;
        double s = 0.0;
        for (int m = 0; m < 4096; m += 256) s += (double)partials[t + m];
        // Collapse lane bits 1..4 (xor 2,4,8,16 preserve bit0 and bit5).
        for (int off = 2; off <= 16; off <<= 1)
            s += __shfl_xor(s, off, 64);
        const int kk = 2 * ((lane >> 5) & 1) + (lane & 1);
        if (lane == 0 || lane == 1 || lane == 32 || lane == 33) klds[wave][kk] = s;
        __syncthreads();
        if (t == 0) {
            double best = -1.0;
            int bi = 0;
            for (int q = 0; q < 4; ++q) {
                double sq = klds[0][q] + klds[1][q] + klds[2][q] + klds[3][q];
                if (sq > best) { best = sq; bi = q; }   // first-max, matches jnp.argmax
            }
            sidx = bi;
            if (blockIdx.x == 0) ((float*)out)[OUT_ELEMS] = (float)bi;
        }
        __syncthreads();
    }
    const int k = sidx;
    const int i = k >> 1;
    const int j = k & 1;
    const int tid = blockIdx.x * 256 + threadIdx.x;
#pragma unroll
    for (int m = 0; m < 8; ++m) {
        int o  = OUT_F4 - 1 - (tid + m * NT);   // descending sweep: hot tail first
        int c4 = o & 31;
        int wq = (o >> 5) & 63;
        int hq = (o >> 11) & 63;
        int b  = o >> 17;
        int vin = b * 524288 + (2 * hq + i) * 4096 + (2 * wq + j) * 32 + c4;
        float4 val = in[vin];
        nfloat4 nval = { val.x, val.y, val.z, val.w };
        __builtin_nontemporal_store(nval, reinterpret_cast<nfloat4*>(&out[o]));
    }
}

extern "C" void kernel_launch(void* const* d_in, const int* in_sizes, int n_in,
                              void* d_out, int out_size, void* d_ws, size_t ws_size,
                              hipStream_t stream) {
    const float4* in = (const float4*)d_in[0];
    float4* out = (float4*)d_out;
    float* partials = (float*)d_ws;   // 4096 floats, fully rewritten every call

    sums_kernel<<<2048, 256, 0, stream>>>(in, partials);
    pick_gather_kernel<<<2048, 256, 0, stream>>>(in, out, partials);
}